// Round 3
// baseline (4644.900 us; speedup 1.0000x reference)
//
#include <hip/hip_runtime.h>

// Problem constants (H=512, A=16, L=3, B=256, T=512)
#define HD 512
#define AD 16
#define BD 256
#define TD 512

using short8  = __attribute__((ext_vector_type(8))) short;
using float4v = __attribute__((ext_vector_type(4))) float;
using ushort4v = __attribute__((ext_vector_type(4))) unsigned short;
typedef unsigned short u16;
typedef unsigned long long u64;

__device__ __forceinline__ u16 f2bf(float f) {
  union { float f; unsigned u; } v; v.f = f;
  unsigned r = v.u + 0x7fffu + ((v.u >> 16) & 1u);
  return (u16)(r >> 16);
}
__device__ __forceinline__ float bf2f(u16 u) {
  union { unsigned u; float f; } c; c.u = ((unsigned)u) << 16; return c.f;
}
// fast sigmoid/tanh via v_exp_f32 (2^x) + v_rcp_f32; rel err ~1e-6, far below bf16 noise
__device__ __forceinline__ float fsigm(float x) {
  return __builtin_amdgcn_rcpf(1.f + __builtin_amdgcn_exp2f(-1.4426950408889634f * x));
}
__device__ __forceinline__ float ftanh(float x) {
  float e = __builtin_amdgcn_exp2f(2.8853900817779268f * x);
  return 1.f - 2.f * __builtin_amdgcn_rcpf(1.f + e);
}

// ---------------- fp32 -> bf16 convert ----------------
__global__ __launch_bounds__(256) void cvt_bf16(const float* __restrict__ in,
                                                u16* __restrict__ out, int n) {
  int i = blockIdx.x * 256 + threadIdx.x;
  int stride = gridDim.x * 256;
  for (; i < n; i += stride) out[i] = f2bf(in[i]);
}

// ---------------- GEMM (M x 512) @ (512 x 512)^T + bias -> LayerNorm -> ReLU -> bf16 ----------------
template <bool AF32>
__global__ __launch_bounds__(256) void gemm_ln_relu(
    const void* __restrict__ Ap, const u16* __restrict__ W,
    const float* __restrict__ bias, const float* __restrict__ gam,
    const float* __restrict__ bet, u16* __restrict__ Y) {
  const int r0 = blockIdx.x * 64;
  const int tid = threadIdx.x;
  const int wave = tid >> 6, lane = tid & 63;
  const int lq = lane >> 4, ln16 = lane & 15;

  __shared__ u16 As[64 * 40];
  __shared__ u16 Bs[512 * 40];
  __shared__ float partial[64][4][2];
  __shared__ float murs[64][2];

  float4v acc[4][8];
#pragma unroll
  for (int i = 0; i < 4; ++i)
#pragma unroll
    for (int j = 0; j < 8; ++j) acc[i][j] = (float4v){0.f, 0.f, 0.f, 0.f};

  for (int kk = 0; kk < 16; ++kk) {
    __syncthreads();
    if (AF32) {
      const float* Af = (const float*)Ap;
#pragma unroll
      for (int it = 0; it < 2; ++it) {
        int q = tid + it * 256;
        int row = q >> 3, ko = (q & 7) * 4;
        float4v v = *(const float4v*)(Af + (r0 + row) * 512 + kk * 32 + ko);
        ushort4v o;
        o[0] = f2bf(v[0]); o[1] = f2bf(v[1]); o[2] = f2bf(v[2]); o[3] = f2bf(v[3]);
        *(ushort4v*)(&As[row * 40 + ko]) = o;
      }
    } else {
      const u16* Ab = (const u16*)Ap;
      int row = tid >> 2, ko = (tid & 3) * 8;
      *(short8*)(&As[row * 40 + ko]) =
          *(const short8*)(Ab + (r0 + row) * 512 + kk * 32 + ko);
    }
#pragma unroll
    for (int it = 0; it < 8; ++it) {
      int q = tid + it * 256;
      int row = q >> 2, ko = (q & 3) * 8;
      *(short8*)(&Bs[row * 40 + ko]) =
          *(const short8*)(W + row * 512 + kk * 32 + ko);
    }
    __syncthreads();
    short8 afr[4];
#pragma unroll
    for (int mt = 0; mt < 4; ++mt)
      afr[mt] = *(const short8*)(&As[(mt * 16 + ln16) * 40 + lq * 8]);
#pragma unroll
    for (int nt = 0; nt < 8; ++nt) {
      short8 bfr = *(const short8*)(&Bs[(wave * 128 + nt * 16 + ln16) * 40 + lq * 8]);
#pragma unroll
      for (int mt = 0; mt < 4; ++mt)
        acc[mt][nt] = __builtin_amdgcn_mfma_f32_16x16x32_bf16(afr[mt], bfr, acc[mt][nt], 0, 0, 0);
    }
  }

  float gv[8], bv[8], av[8];
#pragma unroll
  for (int nt = 0; nt < 8; ++nt) {
    int c = wave * 128 + nt * 16 + ln16;
    gv[nt] = gam[c]; bv[nt] = bet[c]; av[nt] = bias[c];
  }
#pragma unroll
  for (int mt = 0; mt < 4; ++mt)
#pragma unroll
    for (int nt = 0; nt < 8; ++nt)
#pragma unroll
      for (int r = 0; r < 4; ++r) acc[mt][nt][r] += av[nt];

#pragma unroll
  for (int mt = 0; mt < 4; ++mt) {
#pragma unroll
    for (int r = 0; r < 4; ++r) {
      float s = 0.f, ss = 0.f;
#pragma unroll
      for (int nt = 0; nt < 8; ++nt) { float v = acc[mt][nt][r]; s += v; ss += v * v; }
#pragma unroll
      for (int off = 1; off < 16; off <<= 1) { s += __shfl_xor(s, off); ss += __shfl_xor(ss, off); }
      if (ln16 == 0) {
        int m = mt * 16 + lq * 4 + r;
        partial[m][wave][0] = s; partial[m][wave][1] = ss;
      }
    }
  }
  __syncthreads();
  if (tid < 64) {
    float s = partial[tid][0][0] + partial[tid][1][0] + partial[tid][2][0] + partial[tid][3][0];
    float ss = partial[tid][0][1] + partial[tid][1][1] + partial[tid][2][1] + partial[tid][3][1];
    float mu = s * (1.f / 512.f);
    float var = ss * (1.f / 512.f) - mu * mu;
    murs[tid][0] = mu;
    murs[tid][1] = rsqrtf(var + 1e-5f);
  }
  __syncthreads();
#pragma unroll
  for (int mt = 0; mt < 4; ++mt) {
#pragma unroll
    for (int r = 0; r < 4; ++r) {
      int m = mt * 16 + lq * 4 + r;
      float mu = murs[m][0], rs = murs[m][1];
#pragma unroll
      for (int nt = 0; nt < 8; ++nt) {
        int c = wave * 128 + nt * 16 + ln16;
        float v = (acc[mt][nt][r] - mu) * rs * gv[nt] + bv[nt];
        Y[(r0 + m) * 512 + c] = f2bf(fmaxf(v, 0.f));
      }
    }
  }
}

// ---------------- persistent GRU scan v5: per-producer release slots (no RMW) ---------------------
// 256 blocks = 8 bg x 32 cb. Block = 32 batch rows x 16 channels, 4 waves:
//   waves 0,1 = ENGINE (mt = wave): Whh B-fragments in registers. Per step: prefetch dones+gi,
//     poll 32 per-producer slots (lane-parallel loads + __all), 32 pipelined h loads, 48 MFMAs,
//     fast gate math, per-lane u16 h stores, vmcnt(0), then ONE plain agent store of t+1 into this
//     block's own 64B-strided slot (release). No RMW anywhere on the sync path.
//   waves 2,3 = PRODUCER (mt = wave-2): Wih in registers; gi(t+1) into double-buffered scr ring.
//     One __syncthreads per step.
__global__ __launch_bounds__(256, 1) void gru_scan(
    const u16* __restrict__ emb, const u16* __restrict__ wih,
    const u16* __restrict__ whh, const float* __restrict__ bih,
    const float* __restrict__ bhh, const float* __restrict__ hidden,
    const int* __restrict__ dones, float* __restrict__ outs,
    float* __restrict__ hfin, u64* __restrict__ hpk, int* __restrict__ flg) {
  const int bg = blockIdx.x >> 5;
  const int cg = blockIdx.x & 31;
  const int c0 = cg * 16;
  const int b0 = bg * 32;
  const int tid = threadIdx.x;
  const int wave = tid >> 6, lane = tid & 63;
  const int lq = lane >> 4, ln16 = lane & 15;

  __shared__ float scr[2][2][3][16][18];  // [parity][mt][gate][row][col(+pad)]
  u16* hpk16 = (u16*)hpk;

  if (wave < 2) {
    // ================= ENGINE =================
    const int mt = wave;
    const int rowA = b0 + mt * 16 + ln16;  // batch row this lane's A-frag covers

    // Whh B-fragments -> registers, once (48 x short8 = 192 regs; AGPR-backed at this occupancy)
    short8 wr_[48];
#pragma unroll
    for (int g = 0; g < 3; ++g)
#pragma unroll
      for (int kk = 0; kk < 16; ++kk)
        wr_[g * 16 + kk] =
            *(const short8*)(whh + (g * 512 + c0 + ln16) * 512 + kk * 32 + lq * 8);

    float bi[3], bhv[3];
#pragma unroll
    for (int g = 0; g < 3; ++g) {
      bi[g]  = bih[g * 512 + c0 + ln16];
      bhv[g] = bhh[g * 512 + c0 + ln16];
    }
    float hprev[4];
#pragma unroll
    for (int r = 0; r < 4; ++r)
      hprev[r] = hidden[(b0 + mt * 16 + lq * 4 + r) * 512 + c0 + ln16];

    // release slot for THIS engine (written by lane 0 only, 64B stride);
    // poll base for the 32 producers of this (bg,mt) chain (lane-parallel)
    int* myslot = flg + ((bg * 2 + mt) * 32 + cg) * 16;
    const int* pollp = flg + ((bg * 2 + mt) * 32 + (lane & 31)) * 16;

    __syncthreads();  // pairs with producers' post-prime barrier

    for (int t = 0; t < TD; ++t) {
      // ---- off-path prefetches (independent of the flag) ----
      int dnr[4];  // done flag for each C-layout row this lane produces
#pragma unroll
      for (int r = 0; r < 4; ++r)
        dnr[r] = dones[(b0 + mt * 16 + lq * 4 + r) * 512 + t];
      float giv[3][4];
#pragma unroll
      for (int g = 0; g < 3; ++g)
#pragma unroll
        for (int r = 0; r < 4; ++r) giv[g][r] = scr[t & 1][mt][g][lq * 4 + r][ln16];

      // ---- wait: all 32 producers have released step t-1 (slot value >= t) ----
      if (t > 0) {
        int guard = 0;
        for (;;) {
          int v = __hip_atomic_load(pollp, __ATOMIC_RELAXED, __HIP_MEMORY_SCOPE_AGENT);
          if (__all(v >= t)) break;
          if (++guard > (1 << 18)) break;
        }
      }

      // ---- h_{t-1} A-fragments straight into registers (pipelines into the MFMAs below;
      //      reset is applied on the MFMA output) ----
      u64 av[32];
      if (t == 0) {
#pragma unroll
        for (int kk = 0; kk < 16; ++kk) {
          const float* hp = hidden + rowA * 512 + lq * 8 + kk * 32;
          float4v h0 = *(const float4v*)(hp);
          float4v h1 = *(const float4v*)(hp + 4);
          av[2 * kk] = (u64)f2bf(h0[0]) | ((u64)f2bf(h0[1]) << 16) |
                       ((u64)f2bf(h0[2]) << 32) | ((u64)f2bf(h0[3]) << 48);
          av[2 * kk + 1] = (u64)f2bf(h1[0]) | ((u64)f2bf(h1[1]) << 16) |
                           ((u64)f2bf(h1[2]) << 32) | ((u64)f2bf(h1[3]) << 48);
        }
      } else {
        u64* hb = hpk + ((t - 1) & 1) * 32768 + rowA * 128 + lq * 2;
#pragma unroll
        for (int kk = 0; kk < 16; ++kk) {
          av[2 * kk]     = __hip_atomic_load(hb + kk * 8,     __ATOMIC_RELAXED, __HIP_MEMORY_SCOPE_AGENT);
          av[2 * kk + 1] = __hip_atomic_load(hb + kk * 8 + 1, __ATOMIC_RELAXED, __HIP_MEMORY_SCOPE_AGENT);
        }
      }

      // gh = h @ Whh_slice^T  (3 gates), weights from registers
      float4v agh[3];
#pragma unroll
      for (int g = 0; g < 3; ++g) agh[g] = (float4v){0.f, 0.f, 0.f, 0.f};
#pragma unroll
      for (int kk = 0; kk < 16; ++kk) {
        union { u64 q[2]; short8 v; } u;
        u.q[0] = av[2 * kk]; u.q[1] = av[2 * kk + 1];
#pragma unroll
        for (int g = 0; g < 3; ++g)
          agh[g] = __builtin_amdgcn_mfma_f32_16x16x32_bf16(u.v, wr_[g * 16 + kk], agh[g], 0, 0, 0);
      }

      // gate math in C-layout registers (reset: zero the matmul part + zero h)
      float hv[4];
#pragma unroll
      for (int r = 0; r < 4; ++r) {
        bool d = dnr[r] != 0;
        float h  = d ? 0.f : hprev[r];
        float g0 = d ? 0.f : agh[0][r];
        float g1 = d ? 0.f : agh[1][r];
        float g2 = d ? 0.f : agh[2][r];
        float rg = fsigm(giv[0][r] + bi[0] + g0 + bhv[0]);
        float z  = fsigm(giv[1][r] + bi[1] + g1 + bhv[1]);
        float nn = ftanh(giv[2][r] + bi[2] + rg * (g2 + bhv[2]));
        hv[r] = (1.f - z) * nn + z * h;
        hprev[r] = hv[r];
      }

      // per-lane u16 h store
#pragma unroll
      for (int r = 0; r < 4; ++r) {
        int b = b0 + mt * 16 + lq * 4 + r;
        __hip_atomic_store(hpk16 + (t & 1) * 131072 + b * 512 + c0 + ln16,
                           f2bf(hv[r]), __ATOMIC_RELAXED, __HIP_MEMORY_SCOPE_AGENT);
      }
      asm volatile("s_waitcnt vmcnt(0)" ::: "memory");  // h stores at coherent point
      if (lane == 0 && t < TD - 1)
        __hip_atomic_store(myslot, t + 1, __ATOMIC_RELAXED, __HIP_MEMORY_SCOPE_AGENT);

      // off-critical-path global writes (drained by NEXT step's vmcnt(0), fully hidden)
#pragma unroll
      for (int r = 0; r < 4; ++r) {
        int b = b0 + mt * 16 + lq * 4 + r;
        outs[(t * 256 + b) * 512 + c0 + ln16] = hv[r];
        if (t == TD - 1) hfin[b * 512 + c0 + ln16] = hv[r];
      }
      __syncthreads();  // swap gi ring with producers
    }
  } else {
    // ================= PRODUCER =================
    const int mt = wave - 2;

    // Wih B-fragments -> registers, once
    short8 wf[48];
#pragma unroll
    for (int g = 0; g < 3; ++g)
#pragma unroll
      for (int kk = 0; kk < 16; ++kk)
        wf[g * 16 + kk] =
            *(const short8*)(wih + (g * 512 + c0 + ln16) * 512 + kk * 32 + lq * 8);

    const int row = b0 + mt * 16 + ln16;
    auto produce = [&](int tp) {
      const u16* ap = emb + (row * 512 + tp) * 512 + lq * 8;
      float4v acc[3];
#pragma unroll
      for (int g = 0; g < 3; ++g) acc[g] = (float4v){0.f, 0.f, 0.f, 0.f};
#pragma unroll
      for (int kk = 0; kk < 16; ++kk) {
        short8 af = *(const short8*)(ap + kk * 32);
#pragma unroll
        for (int g = 0; g < 3; ++g)
          acc[g] = __builtin_amdgcn_mfma_f32_16x16x32_bf16(af, wf[g * 16 + kk], acc[g], 0, 0, 0);
      }
#pragma unroll
      for (int g = 0; g < 3; ++g)
#pragma unroll
        for (int r = 0; r < 4; ++r)
          scr[tp & 1][mt][g][lq * 4 + r][ln16] = acc[g][r];
    };

    produce(0);        // prime the gi ring
    __syncthreads();   // pairs with engine's pre-loop barrier

    for (int t = 0; t < TD; ++t) {
      if (t + 1 < TD) produce(t + 1);
      __syncthreads();
    }
  }
}

// ---------------- final A=16 projection + avail mask ----------------
__global__ __launch_bounds__(256) void head_logits(
    const u16* __restrict__ am, const float* __restrict__ w2,
    const float* __restrict__ b2, const float* __restrict__ avail,
    float* __restrict__ out) {
  int r = blockIdx.x * 16 + (threadIdx.x >> 4);
  int a = threadIdx.x & 15;
  int t = r >> 8, b = r & 255;
  const u16* ar = am + r * 512;
  const float* wr = w2 + a * 512;
  float acc = 0.f;
  for (int k = 0; k < 512; k += 8) {
    short8 v = *(const short8*)(ar + k);
    float4v w0 = *(const float4v*)(wr + k);
    float4v w1 = *(const float4v*)(wr + k + 4);
    acc += bf2f((u16)v[0]) * w0[0] + bf2f((u16)v[1]) * w0[1] +
           bf2f((u16)v[2]) * w0[2] + bf2f((u16)v[3]) * w0[3] +
           bf2f((u16)v[4]) * w1[0] + bf2f((u16)v[5]) * w1[1] +
           bf2f((u16)v[6]) * w1[2] + bf2f((u16)v[7]) * w1[3];
  }
  int oi = (b * 512 + t) * 16 + a;
  float avv = avail[oi];
  out[oi] = acc + b2[a] - (1.f - avv) * 1e10f;
}

extern "C" void kernel_launch(void* const* d_in, const int* in_sizes, int n_in,
                              void* d_out, int out_size, void* d_ws, size_t ws_size,
                              hipStream_t stream) {
  (void)in_sizes; (void)n_in; (void)out_size; (void)ws_size;
  const float* hidden = (const float*)d_in[0];
  const float* obs    = (const float*)d_in[1];
  const int*   dones  = (const int*)d_in[2];
  const float* avail  = (const float*)d_in[3];
  const float* in_w   = (const float*)d_in[4];
  const float* in_b   = (const float*)d_in[5];
  const float* ln_g   = (const float*)d_in[6];
  const float* ln_b   = (const float*)d_in[7];
  const float* gwih   = (const float*)d_in[8];
  const float* gwhh   = (const float*)d_in[9];
  const float* gbih   = (const float*)d_in[10];
  const float* gbhh   = (const float*)d_in[11];
  const float* am1w   = (const float*)d_in[12];
  const float* am1b   = (const float*)d_in[13];
  const float* amg    = (const float*)d_in[14];
  const float* amb    = (const float*)d_in[15];
  const float* am2w   = (const float*)d_in[16];
  const float* am2b   = (const float*)d_in[17];

  char* ws = (char*)d_ws;
  u16*   embA  = (u16*)(ws);                       // 128 MiB [B*T,512] bf16
  u16*   embB  = (u16*)(ws + 134217728);           // 128 MiB
  float* outs  = (float*)(ws + 268435456);         // 256 MiB [T,B,512] f32
  u16*   w_in  = (u16*)(ws + 536870912);           // bf16 weights
  u16*   w_ih  = w_in + 786432;
  u16*   w_hh  = w_ih + 786432;
  u16*   w_a1  = w_hh + 786432;
  int*   flg   = (int*)(ws + 536870912 + 5242880); // 32 KiB per-(bg,mt,cg) release slots
  u64*   hpk   = (u64*)(ws + 536870912 + 5242880 + 32768); // 512 KiB h ping-pong (packed bf16)

  hipMemsetAsync(flg, 0, 32768, stream);
  cvt_bf16<<<1024, 256, 0, stream>>>(in_w, w_in, 786432);
  cvt_bf16<<<1024, 256, 0, stream>>>(gwih, w_ih, 786432);
  cvt_bf16<<<1024, 256, 0, stream>>>(gwhh, w_hh, 786432);
  cvt_bf16<<<512, 256, 0, stream>>>(am1w, w_a1, 262144);

  // MLP: Linear -> LN -> ReLU x3  (rows in (b,t) order, same as obs)
  gemm_ln_relu<true ><<<2048, 256, 0, stream>>>(obs,  w_in,          in_b,        ln_g,        ln_b,        embA);
  gemm_ln_relu<false><<<2048, 256, 0, stream>>>(embA, w_in + 262144, in_b + 512,  ln_g + 512,  ln_b + 512,  embB);
  gemm_ln_relu<false><<<2048, 256, 0, stream>>>(embB, w_in + 524288, in_b + 1024, ln_g + 1024, ln_b + 1024, embA);

  // GRU scan (persistent, 256 blocks, wave-specialized, RMW-free release/detect)
  gru_scan<<<256, 256, 0, stream>>>(embA, w_ih, w_hh, gbih, gbhh, hidden, dones,
                                    outs, (float*)d_out, hpk, flg);

  // actor head: Linear -> LN -> ReLU (rows in (t,b) order), then A=16 projection + mask
  gemm_ln_relu<true ><<<2048, 256, 0, stream>>>(outs, w_a1, am1b, amg, amb, embB);
  head_logits<<<8192, 256, 0, stream>>>(embB, am2w, am2b, avail, (float*)d_out + 131072);
}

// Round 4
// 4222.736 us; speedup vs baseline: 1.1000x; 1.1000x over previous
//
#include <hip/hip_runtime.h>

// Problem constants (H=512, A=16, L=3, B=256, T=512)
#define HD 512
#define AD 16
#define BD 256
#define TD 512

using short8  = __attribute__((ext_vector_type(8))) short;
using float4v = __attribute__((ext_vector_type(4))) float;
using ushort4v = __attribute__((ext_vector_type(4))) unsigned short;
typedef unsigned short u16;
typedef unsigned long long u64;

__device__ __forceinline__ u16 f2bf(float f) {
  union { float f; unsigned u; } v; v.f = f;
  unsigned r = v.u + 0x7fffu + ((v.u >> 16) & 1u);
  return (u16)(r >> 16);
}
__device__ __forceinline__ float bf2f(u16 u) {
  union { unsigned u; float f; } c; c.u = ((unsigned)u) << 16; return c.f;
}
// fast sigmoid/tanh via v_exp_f32 (2^x) + v_rcp_f32; rel err ~1e-6, far below bf16 noise
__device__ __forceinline__ float fsigm(float x) {
  return __builtin_amdgcn_rcpf(1.f + __builtin_amdgcn_exp2f(-1.4426950408889634f * x));
}
__device__ __forceinline__ float ftanh(float x) {
  float e = __builtin_amdgcn_exp2f(2.8853900817779268f * x);
  return 1.f - 2.f * __builtin_amdgcn_rcpf(1.f + e);
}

// ---------------- fp32 -> bf16 convert ----------------
__global__ __launch_bounds__(256) void cvt_bf16(const float* __restrict__ in,
                                                u16* __restrict__ out, int n) {
  int i = blockIdx.x * 256 + threadIdx.x;
  int stride = gridDim.x * 256;
  for (; i < n; i += stride) out[i] = f2bf(in[i]);
}

// ---------------- GEMM (M x 512) @ (512 x 512)^T + bias -> LayerNorm -> ReLU -> bf16 ----------------
template <bool AF32>
__global__ __launch_bounds__(256) void gemm_ln_relu(
    const void* __restrict__ Ap, const u16* __restrict__ W,
    const float* __restrict__ bias, const float* __restrict__ gam,
    const float* __restrict__ bet, u16* __restrict__ Y) {
  const int r0 = blockIdx.x * 64;
  const int tid = threadIdx.x;
  const int wave = tid >> 6, lane = tid & 63;
  const int lq = lane >> 4, ln16 = lane & 15;

  __shared__ u16 As[64 * 40];
  __shared__ u16 Bs[512 * 40];
  __shared__ float partial[64][4][2];
  __shared__ float murs[64][2];

  float4v acc[4][8];
#pragma unroll
  for (int i = 0; i < 4; ++i)
#pragma unroll
    for (int j = 0; j < 8; ++j) acc[i][j] = (float4v){0.f, 0.f, 0.f, 0.f};

  for (int kk = 0; kk < 16; ++kk) {
    __syncthreads();
    if (AF32) {
      const float* Af = (const float*)Ap;
#pragma unroll
      for (int it = 0; it < 2; ++it) {
        int q = tid + it * 256;
        int row = q >> 3, ko = (q & 7) * 4;
        float4v v = *(const float4v*)(Af + (r0 + row) * 512 + kk * 32 + ko);
        ushort4v o;
        o[0] = f2bf(v[0]); o[1] = f2bf(v[1]); o[2] = f2bf(v[2]); o[3] = f2bf(v[3]);
        *(ushort4v*)(&As[row * 40 + ko]) = o;
      }
    } else {
      const u16* Ab = (const u16*)Ap;
      int row = tid >> 2, ko = (tid & 3) * 8;
      *(short8*)(&As[row * 40 + ko]) =
          *(const short8*)(Ab + (r0 + row) * 512 + kk * 32 + ko);
    }
#pragma unroll
    for (int it = 0; it < 8; ++it) {
      int q = tid + it * 256;
      int row = q >> 2, ko = (q & 3) * 8;
      *(short8*)(&Bs[row * 40 + ko]) =
          *(const short8*)(W + row * 512 + kk * 32 + ko);
    }
    __syncthreads();
    short8 afr[4];
#pragma unroll
    for (int mt = 0; mt < 4; ++mt)
      afr[mt] = *(const short8*)(&As[(mt * 16 + ln16) * 40 + lq * 8]);
#pragma unroll
    for (int nt = 0; nt < 8; ++nt) {
      short8 bfr = *(const short8*)(&Bs[(wave * 128 + nt * 16 + ln16) * 40 + lq * 8]);
#pragma unroll
      for (int mt = 0; mt < 4; ++mt)
        acc[mt][nt] = __builtin_amdgcn_mfma_f32_16x16x32_bf16(afr[mt], bfr, acc[mt][nt], 0, 0, 0);
    }
  }

  float gv[8], bv[8], av[8];
#pragma unroll
  for (int nt = 0; nt < 8; ++nt) {
    int c = wave * 128 + nt * 16 + ln16;
    gv[nt] = gam[c]; bv[nt] = bet[c]; av[nt] = bias[c];
  }
#pragma unroll
  for (int mt = 0; mt < 4; ++mt)
#pragma unroll
    for (int nt = 0; nt < 8; ++nt)
#pragma unroll
      for (int r = 0; r < 4; ++r) acc[mt][nt][r] += av[nt];

#pragma unroll
  for (int mt = 0; mt < 4; ++mt) {
#pragma unroll
    for (int r = 0; r < 4; ++r) {
      float s = 0.f, ss = 0.f;
#pragma unroll
      for (int nt = 0; nt < 8; ++nt) { float v = acc[mt][nt][r]; s += v; ss += v * v; }
#pragma unroll
      for (int off = 1; off < 16; off <<= 1) { s += __shfl_xor(s, off); ss += __shfl_xor(ss, off); }
      if (ln16 == 0) {
        int m = mt * 16 + lq * 4 + r;
        partial[m][wave][0] = s; partial[m][wave][1] = ss;
      }
    }
  }
  __syncthreads();
  if (tid < 64) {
    float s = partial[tid][0][0] + partial[tid][1][0] + partial[tid][2][0] + partial[tid][3][0];
    float ss = partial[tid][0][1] + partial[tid][1][1] + partial[tid][2][1] + partial[tid][3][1];
    float mu = s * (1.f / 512.f);
    float var = ss * (1.f / 512.f) - mu * mu;
    murs[tid][0] = mu;
    murs[tid][1] = rsqrtf(var + 1e-5f);
  }
  __syncthreads();
#pragma unroll
  for (int mt = 0; mt < 4; ++mt) {
#pragma unroll
    for (int r = 0; r < 4; ++r) {
      int m = mt * 16 + lq * 4 + r;
      float mu = murs[m][0], rs = murs[m][1];
#pragma unroll
      for (int nt = 0; nt < 8; ++nt) {
        int c = wave * 128 + nt * 16 + ln16;
        float v = (acc[mt][nt][r] - mu) * rs * gv[nt] + bv[nt];
        Y[(r0 + m) * 512 + c] = f2bf(fmaxf(v, 0.f));
      }
    }
  }
}

// ---------------- persistent GRU scan v6: de-stormed MALL path, barrier-free block ---------------
// 256 blocks = 8 bg x 32 cb. Block = 32 batch rows x 16 channels, 4 waves:
//   waves 0,1 = ENGINE (mt = wave): Whh in registers. Per step: LDS-handshake for gi (no
//     __syncthreads), wave-coalesced 16B asm h loads (sc0 sc1 = device-coherent), 48 MFMAs,
//     fast gates, u16 h stores, vmcnt(0), dense-packed release slot store, outs after.
//     MALL poll: 8 lines (16B-stride slots) + s_sleep backoff.
//   waves 2,3 = PRODUCER (mt = wave-2): Wih in registers; gi ring with pf/ec LDS credit
//     handshake (producer runs up to 2 steps ahead, never blocks the engine).
__global__ __launch_bounds__(256, 1) void gru_scan(
    const u16* __restrict__ emb, const u16* __restrict__ wih,
    const u16* __restrict__ whh, const float* __restrict__ bih,
    const float* __restrict__ bhh, const float* __restrict__ hidden,
    const int* __restrict__ dones, float* __restrict__ outs,
    float* __restrict__ hfin, u64* __restrict__ hpk, int* __restrict__ flg) {
  const int bg = blockIdx.x >> 5;
  const int cg = blockIdx.x & 31;
  const int c0 = cg * 16;
  const int b0 = bg * 32;
  const int tid = threadIdx.x;
  const int wave = tid >> 6, lane = tid & 63;
  const int lq = lane >> 4, ln16 = lane & 15;

  __shared__ float scr[2][2][3][16][18];  // [parity][mt][gate][row][col(+pad)]
  __shared__ int pf[2];  // producer progress: gi(0..pf-1) ready
  __shared__ int ec[2];  // engine progress: gi(0..ec-1) consumed
  u16* hpk16 = (u16*)hpk;

  if (tid == 0) { pf[0] = 0; pf[1] = 0; ec[0] = 0; ec[1] = 0; }
  __syncthreads();  // ONLY barrier in the kernel

  if (wave < 2) {
    // ================= ENGINE =================
    const int mt = wave;
    const int rowA = b0 + mt * 16 + ln16;  // batch row this lane's A-frag covers

    // Whh B-fragments -> registers, once
    short8 wr_[48];
#pragma unroll
    for (int g = 0; g < 3; ++g)
#pragma unroll
      for (int kk = 0; kk < 16; ++kk)
        wr_[g * 16 + kk] =
            *(const short8*)(whh + (g * 512 + c0 + ln16) * 512 + kk * 32 + lq * 8);

    float bi[3], bhv[3];
#pragma unroll
    for (int g = 0; g < 3; ++g) {
      bi[g]  = bih[g * 512 + c0 + ln16];
      bhv[g] = bhh[g * 512 + c0 + ln16];
    }
    float hprev[4];
#pragma unroll
    for (int r = 0; r < 4; ++r)
      hprev[r] = hidden[(b0 + mt * 16 + lq * 4 + r) * 512 + c0 + ln16];

    // dense 16B-stride release slots: chain (bg,mt) spans 32 slots = 512 B = 8 lines
    int* myslot = flg + ((bg * 2 + mt) * 32 + cg) * 4;
    const int* pollp = flg + ((bg * 2 + mt) * 32 + (lane & 31)) * 4;

    for (int t = 0; t < TD; ++t) {
      // ---- gi(t) from producer ring (LDS handshake, usually already ready) ----
      {
        int guard = 0;
        while (__hip_atomic_load(&pf[mt], __ATOMIC_RELAXED, __HIP_MEMORY_SCOPE_WORKGROUP) < t + 1) {
          if (++guard > (1 << 18)) break;
        }
      }
      float giv[3][4];
#pragma unroll
      for (int g = 0; g < 3; ++g)
#pragma unroll
        for (int r = 0; r < 4; ++r) giv[g][r] = scr[t & 1][mt][g][lq * 4 + r][ln16];
      asm volatile("s_waitcnt lgkmcnt(0)" ::: "memory");
      if (lane == 0)
        __hip_atomic_store(&ec[mt], t + 1, __ATOMIC_RELAXED, __HIP_MEMORY_SCOPE_WORKGROUP);

      // ---- off-path dones prefetch ----
      int dnr[4];
#pragma unroll
      for (int r = 0; r < 4; ++r)
        dnr[r] = dones[(b0 + mt * 16 + lq * 4 + r) * 512 + t];

      // ---- MALL poll: all 32 producers released step t-1 (8 lines, backoff spin) ----
      if (t > 0) {
        int guard = 0;
        for (;;) {
          int v = __hip_atomic_load(pollp, __ATOMIC_RELAXED, __HIP_MEMORY_SCOPE_AGENT);
          if (__all(v >= t)) break;
          if (++guard > (1 << 16)) break;
          __builtin_amdgcn_s_sleep(2);
        }
      }

      // ---- h_{t-1} A-fragments: wave-coalesced 16B device-coherent loads ----
      short8 hfr[16];
      if (t == 0) {
#pragma unroll
        for (int kk = 0; kk < 16; ++kk) {
          const float* hp = hidden + rowA * 512 + lq * 8 + kk * 32;
          float4v h0 = *(const float4v*)(hp);
          float4v h1 = *(const float4v*)(hp + 4);
          union { u16 s[8]; short8 v; } u;
          u.s[0] = f2bf(h0[0]); u.s[1] = f2bf(h0[1]); u.s[2] = f2bf(h0[2]); u.s[3] = f2bf(h0[3]);
          u.s[4] = f2bf(h1[0]); u.s[5] = f2bf(h1[1]); u.s[6] = f2bf(h1[2]); u.s[7] = f2bf(h1[3]);
          hfr[kk] = u.v;
        }
      } else {
        const char* hb = (const char*)hpk + ((t - 1) & 1) * 262144 + rowA * 1024 + lq * 16;
#pragma unroll
        for (int kk = 0; kk < 16; ++kk)
          asm volatile("global_load_dwordx4 %0, %1, off offset:%c2 sc0 sc1"
                       : "=v"(hfr[kk]) : "v"(hb), "i"(kk * 64));
        asm volatile("s_waitcnt vmcnt(0)" ::: "memory");
        __builtin_amdgcn_sched_barrier(0);
      }

      // gh = h @ Whh_slice^T  (3 gates), weights from registers
      float4v agh[3];
#pragma unroll
      for (int g = 0; g < 3; ++g) agh[g] = (float4v){0.f, 0.f, 0.f, 0.f};
#pragma unroll
      for (int kk = 0; kk < 16; ++kk)
#pragma unroll
        for (int g = 0; g < 3; ++g)
          agh[g] = __builtin_amdgcn_mfma_f32_16x16x32_bf16(hfr[kk], wr_[g * 16 + kk], agh[g], 0, 0, 0);

      // gate math in C-layout registers (reset: zero the matmul part + zero h)
      float hv[4];
#pragma unroll
      for (int r = 0; r < 4; ++r) {
        bool d = dnr[r] != 0;
        float h  = d ? 0.f : hprev[r];
        float g0 = d ? 0.f : agh[0][r];
        float g1 = d ? 0.f : agh[1][r];
        float g2 = d ? 0.f : agh[2][r];
        float rg = fsigm(giv[0][r] + bi[0] + g0 + bhv[0]);
        float z  = fsigm(giv[1][r] + bi[1] + g1 + bhv[1]);
        float nn = ftanh(giv[2][r] + bi[2] + rg * (g2 + bhv[2]));
        hv[r] = (1.f - z) * nn + z * h;
        hprev[r] = hv[r];
      }

      // per-lane u16 h store
#pragma unroll
      for (int r = 0; r < 4; ++r) {
        int b = b0 + mt * 16 + lq * 4 + r;
        __hip_atomic_store(hpk16 + (t & 1) * 131072 + b * 512 + c0 + ln16,
                           f2bf(hv[r]), __ATOMIC_RELAXED, __HIP_MEMORY_SCOPE_AGENT);
      }
      asm volatile("s_waitcnt vmcnt(0)" ::: "memory");  // h stores at coherent point
      if (lane == 0 && t < TD - 1)
        __hip_atomic_store(myslot, t + 1, __ATOMIC_RELAXED, __HIP_MEMORY_SCOPE_AGENT);

      // off-critical-path global writes
#pragma unroll
      for (int r = 0; r < 4; ++r) {
        int b = b0 + mt * 16 + lq * 4 + r;
        outs[(t * 256 + b) * 512 + c0 + ln16] = hv[r];
        if (t == TD - 1) hfin[b * 512 + c0 + ln16] = hv[r];
      }
    }
  } else {
    // ================= PRODUCER =================
    const int mt = wave - 2;

    // Wih B-fragments -> registers, once
    short8 wf[48];
#pragma unroll
    for (int g = 0; g < 3; ++g)
#pragma unroll
      for (int kk = 0; kk < 16; ++kk)
        wf[g * 16 + kk] =
            *(const short8*)(wih + (g * 512 + c0 + ln16) * 512 + kk * 32 + lq * 8);

    const int row = b0 + mt * 16 + ln16;
    auto produce = [&](int tp) {
      const u16* ap = emb + (row * 512 + tp) * 512 + lq * 8;
      float4v acc[3];
#pragma unroll
      for (int g = 0; g < 3; ++g) acc[g] = (float4v){0.f, 0.f, 0.f, 0.f};
#pragma unroll
      for (int kk = 0; kk < 16; ++kk) {
        short8 af = *(const short8*)(ap + kk * 32);
#pragma unroll
        for (int g = 0; g < 3; ++g)
          acc[g] = __builtin_amdgcn_mfma_f32_16x16x32_bf16(af, wf[g * 16 + kk], acc[g], 0, 0, 0);
      }
#pragma unroll
      for (int g = 0; g < 3; ++g)
#pragma unroll
        for (int r = 0; r < 4; ++r)
          scr[tp & 1][mt][g][lq * 4 + r][ln16] = acc[g][r];
      asm volatile("s_waitcnt lgkmcnt(0)" ::: "memory");
      if (lane == 0)
        __hip_atomic_store(&pf[mt], tp + 1, __ATOMIC_RELAXED, __HIP_MEMORY_SCOPE_WORKGROUP);
    };

    produce(0);  // prime ring slots 0,1 (2-deep lookahead)
    produce(1);
    for (int tp = 2; tp < TD; ++tp) {
      // credit: engine must have consumed gi(tp-2) before slot (tp&1) is overwritten
      int guard = 0;
      while (__hip_atomic_load(&ec[mt], __ATOMIC_RELAXED, __HIP_MEMORY_SCOPE_WORKGROUP) < tp - 1) {
        if (++guard > (1 << 18)) break;
      }
      produce(tp);
    }
  }
}

// ---------------- final A=16 projection + avail mask ----------------
__global__ __launch_bounds__(256) void head_logits(
    const u16* __restrict__ am, const float* __restrict__ w2,
    const float* __restrict__ b2, const float* __restrict__ avail,
    float* __restrict__ out) {
  int r = blockIdx.x * 16 + (threadIdx.x >> 4);
  int a = threadIdx.x & 15;
  int t = r >> 8, b = r & 255;
  const u16* ar = am + r * 512;
  const float* wr = w2 + a * 512;
  float acc = 0.f;
  for (int k = 0; k < 512; k += 8) {
    short8 v = *(const short8*)(ar + k);
    float4v w0 = *(const float4v*)(wr + k);
    float4v w1 = *(const float4v*)(wr + k + 4);
    acc += bf2f((u16)v[0]) * w0[0] + bf2f((u16)v[1]) * w0[1] +
           bf2f((u16)v[2]) * w0[2] + bf2f((u16)v[3]) * w0[3] +
           bf2f((u16)v[4]) * w1[0] + bf2f((u16)v[5]) * w1[1] +
           bf2f((u16)v[6]) * w1[2] + bf2f((u16)v[7]) * w1[3];
  }
  int oi = (b * 512 + t) * 16 + a;
  float avv = avail[oi];
  out[oi] = acc + b2[a] - (1.f - avv) * 1e10f;
}

extern "C" void kernel_launch(void* const* d_in, const int* in_sizes, int n_in,
                              void* d_out, int out_size, void* d_ws, size_t ws_size,
                              hipStream_t stream) {
  (void)in_sizes; (void)n_in; (void)out_size; (void)ws_size;
  const float* hidden = (const float*)d_in[0];
  const float* obs    = (const float*)d_in[1];
  const int*   dones  = (const int*)d_in[2];
  const float* avail  = (const float*)d_in[3];
  const float* in_w   = (const float*)d_in[4];
  const float* in_b   = (const float*)d_in[5];
  const float* ln_g   = (const float*)d_in[6];
  const float* ln_b   = (const float*)d_in[7];
  const float* gwih   = (const float*)d_in[8];
  const float* gwhh   = (const float*)d_in[9];
  const float* gbih   = (const float*)d_in[10];
  const float* gbhh   = (const float*)d_in[11];
  const float* am1w   = (const float*)d_in[12];
  const float* am1b   = (const float*)d_in[13];
  const float* amg    = (const float*)d_in[14];
  const float* amb    = (const float*)d_in[15];
  const float* am2w   = (const float*)d_in[16];
  const float* am2b   = (const float*)d_in[17];

  char* ws = (char*)d_ws;
  u16*   embA  = (u16*)(ws);                       // 128 MiB [B*T,512] bf16
  u16*   embB  = (u16*)(ws + 134217728);           // 128 MiB
  float* outs  = (float*)(ws + 268435456);         // 256 MiB [T,B,512] f32
  u16*   w_in  = (u16*)(ws + 536870912);           // bf16 weights
  u16*   w_ih  = w_in + 786432;
  u16*   w_hh  = w_ih + 786432;
  u16*   w_a1  = w_hh + 786432;
  int*   flg   = (int*)(ws + 536870912 + 5242880); // release slots (16B stride, dense)
  u64*   hpk   = (u64*)(ws + 536870912 + 5242880 + 32768); // 512 KiB h ping-pong (packed bf16)

  hipMemsetAsync(flg, 0, 32768, stream);
  cvt_bf16<<<1024, 256, 0, stream>>>(in_w, w_in, 786432);
  cvt_bf16<<<1024, 256, 0, stream>>>(gwih, w_ih, 786432);
  cvt_bf16<<<1024, 256, 0, stream>>>(gwhh, w_hh, 786432);
  cvt_bf16<<<512, 256, 0, stream>>>(am1w, w_a1, 262144);

  // MLP: Linear -> LN -> ReLU x3  (rows in (b,t) order, same as obs)
  gemm_ln_relu<true ><<<2048, 256, 0, stream>>>(obs,  w_in,          in_b,        ln_g,        ln_b,        embA);
  gemm_ln_relu<false><<<2048, 256, 0, stream>>>(embA, w_in + 262144, in_b + 512,  ln_g + 512,  ln_b + 512,  embB);
  gemm_ln_relu<false><<<2048, 256, 0, stream>>>(embB, w_in + 524288, in_b + 1024, ln_g + 1024, ln_b + 1024, embA);

  // GRU scan (persistent, 256 blocks, de-stormed device-scope exchange)
  gru_scan<<<256, 256, 0, stream>>>(embA, w_ih, w_hh, gbih, gbhh, hidden, dones,
                                    outs, (float*)d_out, hpk, flg);

  // actor head: Linear -> LN -> ReLU (rows in (t,b) order), then A=16 projection + mask
  gemm_ln_relu<true ><<<2048, 256, 0, stream>>>(outs, w_a1, am1b, amg, amb, embB);
  head_logits<<<8192, 256, 0, stream>>>(embB, am2w, am2b, avail, (float*)d_out + 131072);
}

// Round 5
// 4102.038 us; speedup vs baseline: 1.1323x; 1.0294x over previous
//
#include <hip/hip_runtime.h>

// Problem constants (H=512, A=16, L=3, B=256, T=512)
#define HD 512
#define AD 16
#define BD 256
#define TD 512

using short8  = __attribute__((ext_vector_type(8))) short;
using float4v = __attribute__((ext_vector_type(4))) float;
using ushort4v = __attribute__((ext_vector_type(4))) unsigned short;
typedef unsigned short u16;
typedef unsigned long long u64;

// global -> LDS direct DMA, 16B per lane (dest = uniform base + lane*16)
#define GLOAD_LDS16(gsrc, ldst)                                                  \
  __builtin_amdgcn_global_load_lds(                                              \
      (const __attribute__((address_space(1))) void*)(gsrc),                     \
      (__attribute__((address_space(3))) void*)(ldst), 16, 0, 0)

__device__ __forceinline__ u16 f2bf(float f) {
  union { float f; unsigned u; } v; v.f = f;
  unsigned r = v.u + 0x7fffu + ((v.u >> 16) & 1u);
  return (u16)(r >> 16);
}
__device__ __forceinline__ float bf2f(u16 u) {
  union { unsigned u; float f; } c; c.u = ((unsigned)u) << 16; return c.f;
}
// fast sigmoid/tanh via v_exp_f32 (2^x) + v_rcp_f32; rel err ~1e-6, far below bf16 noise
__device__ __forceinline__ float fsigm(float x) {
  return __builtin_amdgcn_rcpf(1.f + __builtin_amdgcn_exp2f(-1.4426950408889634f * x));
}
__device__ __forceinline__ float ftanh(float x) {
  float e = __builtin_amdgcn_exp2f(2.8853900817779268f * x);
  return 1.f - 2.f * __builtin_amdgcn_rcpf(1.f + e);
}

// ---------------- fp32 -> bf16 convert ----------------
__global__ __launch_bounds__(256) void cvt_bf16(const float* __restrict__ in,
                                                u16* __restrict__ out, int n) {
  int i = blockIdx.x * 256 + threadIdx.x;
  int stride = gridDim.x * 256;
  for (; i < n; i += stride) out[i] = f2bf(in[i]);
}

// ---------------- GEMM (M x 512) @ (512 x 512)^T + bias -> LayerNorm -> ReLU -> bf16 -------------
// m97-structure K-loop: linear (unpadded) LDS tiles staged via global_load_lds width-16 DMA,
// 2 barriers per K-step. Block = 64 rows x 512 cols (full rows so LN fuses), 4 waves x 128 cols.
template <bool AF32>
__global__ __launch_bounds__(256) void gemm_ln_relu(
    const void* __restrict__ Ap, const u16* __restrict__ W,
    const float* __restrict__ bias, const float* __restrict__ gam,
    const float* __restrict__ bet, u16* __restrict__ Y) {
  const int r0 = blockIdx.x * 64;
  const int tid = threadIdx.x;
  const int wave = tid >> 6, lane = tid & 63;
  const int lq = lane >> 4, ln16 = lane & 15;

  __shared__ u16 As[64 * 32];    // [row][k] linear, 4 KB
  __shared__ u16 Bs[512 * 32];   // [col-row][k] linear, 32 KB
  __shared__ float partial[64][4][2];
  __shared__ float murs[64][2];

  float4v acc[4][8];
#pragma unroll
  for (int i = 0; i < 4; ++i)
#pragma unroll
    for (int j = 0; j < 8; ++j) acc[i][j] = (float4v){0.f, 0.f, 0.f, 0.f};

  for (int kk = 0; kk < 16; ++kk) {
    // ---- stage A tile [64][32] ----
    if (AF32) {
      const float* Af = (const float*)Ap;
      int row = tid >> 2, ko = (tid & 3) * 8;
      const float* ap = Af + (r0 + row) * 512 + kk * 32 + ko;
      float4v v0 = *(const float4v*)(ap);
      float4v v1 = *(const float4v*)(ap + 4);
      union { u16 s[8]; short8 v; } u;
      u.s[0] = f2bf(v0[0]); u.s[1] = f2bf(v0[1]); u.s[2] = f2bf(v0[2]); u.s[3] = f2bf(v0[3]);
      u.s[4] = f2bf(v1[0]); u.s[5] = f2bf(v1[1]); u.s[6] = f2bf(v1[2]); u.s[7] = f2bf(v1[3]);
      *(short8*)(&As[row * 32 + ko]) = u.v;
    } else {
      const u16* Ab = (const u16*)Ap;
      // one DMA per wave: 64 lanes x 16 B = 16 rows
      int row = wave * 16 + (lane >> 2), c = lane & 3;
      GLOAD_LDS16(Ab + (r0 + row) * 512 + kk * 32 + c * 8, &As[wave * 512]);
    }
    // ---- stage B tile [512][32]: 8 DMA instrs per wave ----
#pragma unroll
    for (int it = 0; it < 8; ++it) {
      int i = it * 4 + wave;                    // instr index 0..31
      int row = i * 16 + (lane >> 2), c = lane & 3;
      GLOAD_LDS16(W + row * 512 + kk * 32 + c * 8, &Bs[i * 512]);
    }
    __syncthreads();  // drains vmcnt (DMA) + lgkm (ds_write) before reads

    short8 afr[4];
#pragma unroll
    for (int mt = 0; mt < 4; ++mt)
      afr[mt] = *(const short8*)(&As[(mt * 16 + ln16) * 32 + lq * 8]);
#pragma unroll
    for (int nt = 0; nt < 8; ++nt) {
      short8 bfr = *(const short8*)(&Bs[(wave * 128 + nt * 16 + ln16) * 32 + lq * 8]);
#pragma unroll
      for (int mt = 0; mt < 4; ++mt)
        acc[mt][nt] = __builtin_amdgcn_mfma_f32_16x16x32_bf16(afr[mt], bfr, acc[mt][nt], 0, 0, 0);
    }
    __syncthreads();  // LDS reuse protection for next K-step
  }

  float gv[8], bv[8], av[8];
#pragma unroll
  for (int nt = 0; nt < 8; ++nt) {
    int c = wave * 128 + nt * 16 + ln16;
    gv[nt] = gam[c]; bv[nt] = bet[c]; av[nt] = bias[c];
  }
#pragma unroll
  for (int mt = 0; mt < 4; ++mt)
#pragma unroll
    for (int nt = 0; nt < 8; ++nt)
#pragma unroll
      for (int r = 0; r < 4; ++r) acc[mt][nt][r] += av[nt];

#pragma unroll
  for (int mt = 0; mt < 4; ++mt) {
#pragma unroll
    for (int r = 0; r < 4; ++r) {
      float s = 0.f, ss = 0.f;
#pragma unroll
      for (int nt = 0; nt < 8; ++nt) { float v = acc[mt][nt][r]; s += v; ss += v * v; }
#pragma unroll
      for (int off = 1; off < 16; off <<= 1) { s += __shfl_xor(s, off); ss += __shfl_xor(ss, off); }
      if (ln16 == 0) {
        int m = mt * 16 + lq * 4 + r;
        partial[m][wave][0] = s; partial[m][wave][1] = ss;
      }
    }
  }
  __syncthreads();
  if (tid < 64) {
    float s = partial[tid][0][0] + partial[tid][1][0] + partial[tid][2][0] + partial[tid][3][0];
    float ss = partial[tid][0][1] + partial[tid][1][1] + partial[tid][2][1] + partial[tid][3][1];
    float mu = s * (1.f / 512.f);
    float var = ss * (1.f / 512.f) - mu * mu;
    murs[tid][0] = mu;
    murs[tid][1] = rsqrtf(var + 1e-5f);
  }
  __syncthreads();
#pragma unroll
  for (int mt = 0; mt < 4; ++mt) {
#pragma unroll
    for (int r = 0; r < 4; ++r) {
      int m = mt * 16 + lq * 4 + r;
      float mu = murs[m][0], rs = murs[m][1];
#pragma unroll
      for (int nt = 0; nt < 8; ++nt) {
        int c = wave * 128 + nt * 16 + ln16;
        float v = (acc[mt][nt][r] - mu) * rs * gv[nt] + bv[nt];
        Y[(r0 + m) * 512 + c] = f2bf(fmaxf(v, 0.f));
      }
    }
  }
}

// ---------------- persistent GRU scan v6: de-stormed MALL path, barrier-free block ---------------
// (unchanged from last round: 8 bg x 32 cb, engines with Whh in registers, coalesced sc0/sc1
//  h exchange, dense release slots + s_sleep poll, LDS credit handshake with producers)
__global__ __launch_bounds__(256, 1) void gru_scan(
    const u16* __restrict__ emb, const u16* __restrict__ wih,
    const u16* __restrict__ whh, const float* __restrict__ bih,
    const float* __restrict__ bhh, const float* __restrict__ hidden,
    const int* __restrict__ dones, float* __restrict__ outs,
    float* __restrict__ hfin, u64* __restrict__ hpk, int* __restrict__ flg) {
  const int bg = blockIdx.x >> 5;
  const int cg = blockIdx.x & 31;
  const int c0 = cg * 16;
  const int b0 = bg * 32;
  const int tid = threadIdx.x;
  const int wave = tid >> 6, lane = tid & 63;
  const int lq = lane >> 4, ln16 = lane & 15;

  __shared__ float scr[2][2][3][16][18];  // [parity][mt][gate][row][col(+pad)]
  __shared__ int pf[2];  // producer progress: gi(0..pf-1) ready
  __shared__ int ec[2];  // engine progress: gi(0..ec-1) consumed
  u16* hpk16 = (u16*)hpk;

  if (tid == 0) { pf[0] = 0; pf[1] = 0; ec[0] = 0; ec[1] = 0; }
  __syncthreads();  // ONLY barrier in the kernel

  if (wave < 2) {
    // ================= ENGINE =================
    const int mt = wave;
    const int rowA = b0 + mt * 16 + ln16;  // batch row this lane's A-frag covers

    // Whh B-fragments -> registers, once
    short8 wr_[48];
#pragma unroll
    for (int g = 0; g < 3; ++g)
#pragma unroll
      for (int kk = 0; kk < 16; ++kk)
        wr_[g * 16 + kk] =
            *(const short8*)(whh + (g * 512 + c0 + ln16) * 512 + kk * 32 + lq * 8);

    float bi[3], bhv[3];
#pragma unroll
    for (int g = 0; g < 3; ++g) {
      bi[g]  = bih[g * 512 + c0 + ln16];
      bhv[g] = bhh[g * 512 + c0 + ln16];
    }
    float hprev[4];
#pragma unroll
    for (int r = 0; r < 4; ++r)
      hprev[r] = hidden[(b0 + mt * 16 + lq * 4 + r) * 512 + c0 + ln16];

    // dense 16B-stride release slots: chain (bg,mt) spans 32 slots = 512 B = 8 lines
    int* myslot = flg + ((bg * 2 + mt) * 32 + cg) * 4;
    const int* pollp = flg + ((bg * 2 + mt) * 32 + (lane & 31)) * 4;

    for (int t = 0; t < TD; ++t) {
      // ---- gi(t) from producer ring (LDS handshake, usually already ready) ----
      {
        int guard = 0;
        while (__hip_atomic_load(&pf[mt], __ATOMIC_RELAXED, __HIP_MEMORY_SCOPE_WORKGROUP) < t + 1) {
          if (++guard > (1 << 18)) break;
        }
      }
      float giv[3][4];
#pragma unroll
      for (int g = 0; g < 3; ++g)
#pragma unroll
        for (int r = 0; r < 4; ++r) giv[g][r] = scr[t & 1][mt][g][lq * 4 + r][ln16];
      asm volatile("s_waitcnt lgkmcnt(0)" ::: "memory");
      if (lane == 0)
        __hip_atomic_store(&ec[mt], t + 1, __ATOMIC_RELAXED, __HIP_MEMORY_SCOPE_WORKGROUP);

      // ---- off-path dones prefetch ----
      int dnr[4];
#pragma unroll
      for (int r = 0; r < 4; ++r)
        dnr[r] = dones[(b0 + mt * 16 + lq * 4 + r) * 512 + t];

      // ---- MALL poll: all 32 producers released step t-1 (8 lines, backoff spin) ----
      if (t > 0) {
        int guard = 0;
        for (;;) {
          int v = __hip_atomic_load(pollp, __ATOMIC_RELAXED, __HIP_MEMORY_SCOPE_AGENT);
          if (__all(v >= t)) break;
          if (++guard > (1 << 16)) break;
          __builtin_amdgcn_s_sleep(2);
        }
      }

      // ---- h_{t-1} A-fragments: wave-coalesced 16B device-coherent loads ----
      short8 hfr[16];
      if (t == 0) {
#pragma unroll
        for (int kk = 0; kk < 16; ++kk) {
          const float* hp = hidden + rowA * 512 + lq * 8 + kk * 32;
          float4v h0 = *(const float4v*)(hp);
          float4v h1 = *(const float4v*)(hp + 4);
          union { u16 s[8]; short8 v; } u;
          u.s[0] = f2bf(h0[0]); u.s[1] = f2bf(h0[1]); u.s[2] = f2bf(h0[2]); u.s[3] = f2bf(h0[3]);
          u.s[4] = f2bf(h1[0]); u.s[5] = f2bf(h1[1]); u.s[6] = f2bf(h1[2]); u.s[7] = f2bf(h1[3]);
          hfr[kk] = u.v;
        }
      } else {
        const char* hb = (const char*)hpk + ((t - 1) & 1) * 262144 + rowA * 1024 + lq * 16;
#pragma unroll
        for (int kk = 0; kk < 16; ++kk)
          asm volatile("global_load_dwordx4 %0, %1, off offset:%c2 sc0 sc1"
                       : "=v"(hfr[kk]) : "v"(hb), "i"(kk * 64));
        asm volatile("s_waitcnt vmcnt(0)" ::: "memory");
        __builtin_amdgcn_sched_barrier(0);
      }

      // gh = h @ Whh_slice^T  (3 gates), weights from registers
      float4v agh[3];
#pragma unroll
      for (int g = 0; g < 3; ++g) agh[g] = (float4v){0.f, 0.f, 0.f, 0.f};
#pragma unroll
      for (int kk = 0; kk < 16; ++kk)
#pragma unroll
        for (int g = 0; g < 3; ++g)
          agh[g] = __builtin_amdgcn_mfma_f32_16x16x32_bf16(hfr[kk], wr_[g * 16 + kk], agh[g], 0, 0, 0);

      // gate math in C-layout registers (reset: zero the matmul part + zero h)
      float hv[4];
#pragma unroll
      for (int r = 0; r < 4; ++r) {
        bool d = dnr[r] != 0;
        float h  = d ? 0.f : hprev[r];
        float g0 = d ? 0.f : agh[0][r];
        float g1 = d ? 0.f : agh[1][r];
        float g2 = d ? 0.f : agh[2][r];
        float rg = fsigm(giv[0][r] + bi[0] + g0 + bhv[0]);
        float z  = fsigm(giv[1][r] + bi[1] + g1 + bhv[1]);
        float nn = ftanh(giv[2][r] + bi[2] + rg * (g2 + bhv[2]));
        hv[r] = (1.f - z) * nn + z * h;
        hprev[r] = hv[r];
      }

      // per-lane u16 h store
#pragma unroll
      for (int r = 0; r < 4; ++r) {
        int b = b0 + mt * 16 + lq * 4 + r;
        __hip_atomic_store(hpk16 + (t & 1) * 131072 + b * 512 + c0 + ln16,
                           f2bf(hv[r]), __ATOMIC_RELAXED, __HIP_MEMORY_SCOPE_AGENT);
      }
      asm volatile("s_waitcnt vmcnt(0)" ::: "memory");  // h stores at coherent point
      if (lane == 0 && t < TD - 1)
        __hip_atomic_store(myslot, t + 1, __ATOMIC_RELAXED, __HIP_MEMORY_SCOPE_AGENT);

      // off-critical-path global writes
#pragma unroll
      for (int r = 0; r < 4; ++r) {
        int b = b0 + mt * 16 + lq * 4 + r;
        outs[(t * 256 + b) * 512 + c0 + ln16] = hv[r];
        if (t == TD - 1) hfin[b * 512 + c0 + ln16] = hv[r];
      }
    }
  } else {
    // ================= PRODUCER =================
    const int mt = wave - 2;

    // Wih B-fragments -> registers, once
    short8 wf[48];
#pragma unroll
    for (int g = 0; g < 3; ++g)
#pragma unroll
      for (int kk = 0; kk < 16; ++kk)
        wf[g * 16 + kk] =
            *(const short8*)(wih + (g * 512 + c0 + ln16) * 512 + kk * 32 + lq * 8);

    const int row = b0 + mt * 16 + ln16;
    auto produce = [&](int tp) {
      const u16* ap = emb + (row * 512 + tp) * 512 + lq * 8;
      float4v acc[3];
#pragma unroll
      for (int g = 0; g < 3; ++g) acc[g] = (float4v){0.f, 0.f, 0.f, 0.f};
#pragma unroll
      for (int kk = 0; kk < 16; ++kk) {
        short8 af = *(const short8*)(ap + kk * 32);
#pragma unroll
        for (int g = 0; g < 3; ++g)
          acc[g] = __builtin_amdgcn_mfma_f32_16x16x32_bf16(af, wf[g * 16 + kk], acc[g], 0, 0, 0);
      }
#pragma unroll
      for (int g = 0; g < 3; ++g)
#pragma unroll
        for (int r = 0; r < 4; ++r)
          scr[tp & 1][mt][g][lq * 4 + r][ln16] = acc[g][r];
      asm volatile("s_waitcnt lgkmcnt(0)" ::: "memory");
      if (lane == 0)
        __hip_atomic_store(&pf[mt], tp + 1, __ATOMIC_RELAXED, __HIP_MEMORY_SCOPE_WORKGROUP);
    };

    produce(0);  // prime ring slots 0,1 (2-deep lookahead)
    produce(1);
    for (int tp = 2; tp < TD; ++tp) {
      // credit: engine must have consumed gi(tp-2) before slot (tp&1) is overwritten
      int guard = 0;
      while (__hip_atomic_load(&ec[mt], __ATOMIC_RELAXED, __HIP_MEMORY_SCOPE_WORKGROUP) < tp - 1) {
        if (++guard > (1 << 18)) break;
      }
      produce(tp);
    }
  }
}

// ---------------- final A=16 projection + avail mask ----------------
__global__ __launch_bounds__(256) void head_logits(
    const u16* __restrict__ am, const float* __restrict__ w2,
    const float* __restrict__ b2, const float* __restrict__ avail,
    float* __restrict__ out) {
  int r = blockIdx.x * 16 + (threadIdx.x >> 4);
  int a = threadIdx.x & 15;
  int t = r >> 8, b = r & 255;
  const u16* ar = am + r * 512;
  const float* wr = w2 + a * 512;
  float acc = 0.f;
  for (int k = 0; k < 512; k += 8) {
    short8 v = *(const short8*)(ar + k);
    float4v w0 = *(const float4v*)(wr + k);
    float4v w1 = *(const float4v*)(wr + k + 4);
    acc += bf2f((u16)v[0]) * w0[0] + bf2f((u16)v[1]) * w0[1] +
           bf2f((u16)v[2]) * w0[2] + bf2f((u16)v[3]) * w0[3] +
           bf2f((u16)v[4]) * w1[0] + bf2f((u16)v[5]) * w1[1] +
           bf2f((u16)v[6]) * w1[2] + bf2f((u16)v[7]) * w1[3];
  }
  int oi = (b * 512 + t) * 16 + a;
  float avv = avail[oi];
  out[oi] = acc + b2[a] - (1.f - avv) * 1e10f;
}

extern "C" void kernel_launch(void* const* d_in, const int* in_sizes, int n_in,
                              void* d_out, int out_size, void* d_ws, size_t ws_size,
                              hipStream_t stream) {
  (void)in_sizes; (void)n_in; (void)out_size; (void)ws_size;
  const float* hidden = (const float*)d_in[0];
  const float* obs    = (const float*)d_in[1];
  const int*   dones  = (const int*)d_in[2];
  const float* avail  = (const float*)d_in[3];
  const float* in_w   = (const float*)d_in[4];
  const float* in_b   = (const float*)d_in[5];
  const float* ln_g   = (const float*)d_in[6];
  const float* ln_b   = (const float*)d_in[7];
  const float* gwih   = (const float*)d_in[8];
  const float* gwhh   = (const float*)d_in[9];
  const float* gbih   = (const float*)d_in[10];
  const float* gbhh   = (const float*)d_in[11];
  const float* am1w   = (const float*)d_in[12];
  const float* am1b   = (const float*)d_in[13];
  const float* amg    = (const float*)d_in[14];
  const float* amb    = (const float*)d_in[15];
  const float* am2w   = (const float*)d_in[16];
  const float* am2b   = (const float*)d_in[17];

  char* ws = (char*)d_ws;
  u16*   embA  = (u16*)(ws);                       // 128 MiB [B*T,512] bf16
  u16*   embB  = (u16*)(ws + 134217728);           // 128 MiB
  float* outs  = (float*)(ws + 268435456);         // 256 MiB [T,B,512] f32
  u16*   w_in  = (u16*)(ws + 536870912);           // bf16 weights
  u16*   w_ih  = w_in + 786432;
  u16*   w_hh  = w_ih + 786432;
  u16*   w_a1  = w_hh + 786432;
  int*   flg   = (int*)(ws + 536870912 + 5242880); // release slots (16B stride, dense)
  u64*   hpk   = (u64*)(ws + 536870912 + 5242880 + 32768); // 512 KiB h ping-pong (packed bf16)

  hipMemsetAsync(flg, 0, 32768, stream);
  cvt_bf16<<<1024, 256, 0, stream>>>(in_w, w_in, 786432);
  cvt_bf16<<<1024, 256, 0, stream>>>(gwih, w_ih, 786432);
  cvt_bf16<<<1024, 256, 0, stream>>>(gwhh, w_hh, 786432);
  cvt_bf16<<<512, 256, 0, stream>>>(am1w, w_a1, 262144);

  // MLP: Linear -> LN -> ReLU x3  (rows in (b,t) order, same as obs)
  gemm_ln_relu<true ><<<2048, 256, 0, stream>>>(obs,  w_in,          in_b,        ln_g,        ln_b,        embA);
  gemm_ln_relu<false><<<2048, 256, 0, stream>>>(embA, w_in + 262144, in_b + 512,  ln_g + 512,  ln_b + 512,  embB);
  gemm_ln_relu<false><<<2048, 256, 0, stream>>>(embB, w_in + 524288, in_b + 1024, ln_g + 1024, ln_b + 1024, embA);

  // GRU scan (persistent, 256 blocks, de-stormed device-scope exchange)
  gru_scan<<<256, 256, 0, stream>>>(embA, w_ih, w_hh, gbih, gbhh, hidden, dones,
                                    outs, (float*)d_out, hpk, flg);

  // actor head: Linear -> LN -> ReLU (rows in (t,b) order), then A=16 projection + mask
  gemm_ln_relu<true ><<<2048, 256, 0, stream>>>(outs, w_a1, am1b, amg, amb, embB);
  head_logits<<<8192, 256, 0, stream>>>(embB, am2w, am2b, avail, (float*)d_out + 131072);
}